// Round 11
// baseline (1967.063 us; speedup 1.0000x reference)
//
#include <hip/hip_runtime.h>

// Problem constants
#define BTOT 1024
#define TPTS 96
#define NV   7
#define HD   64
#define NH   256

typedef short bf16x8 __attribute__((ext_vector_type(8)));
typedef float f32x4  __attribute__((ext_vector_type(4)));
typedef unsigned int u32x4 __attribute__((ext_vector_type(4)));
#define MFMA16(a,b,c) __builtin_amdgcn_mfma_f32_16x16x32_bf16(a,b,c,0,0,0)

// LDS layout (32-bit word offsets), total 20176 words = 80704 B (1 block/CU)
#define OFF_YP   0        // 2 planes x [16 rows][32 words], XOR-swizzled   = 1024
#define OFF_TP   1024     // 2 planes x [16 rows][128 words], XOR-swizzled  = 4096
#define OFF_YF   5120     // f32 [16][65]                                   = 1040
#define OFF_PS   6160     // f32 [4 nt][16 rows] row-sum partials           = 64
#define OFF_TPS  6224     // 96
#define OFF_DW1  6320     // f32 [3][64][64]                                = 12288
#define OFF_DW2  18608    // f32 [3][64][7]                                 = 1344
#define OFF_DB1  19952    // 192
#define OFF_DB2  20144    // 32 (21 used)
#define SMEM_WORDS 20176
#define SMEM_BYTES (SMEM_WORDS*4)

__device__ __forceinline__ float rdlane(float v, int i) {
    return __int_as_float(__builtin_amdgcn_readlane(__float_as_int(v), i));
}
__device__ __forceinline__ float wsum64(float v) {
    v += __shfl_xor(v, 1);  v += __shfl_xor(v, 2);  v += __shfl_xor(v, 4);
    v += __shfl_xor(v, 8);  v += __shfl_xor(v, 16); v += __shfl_xor(v, 32);
    return v;
}
__device__ __forceinline__ float tanh_fast(float x) {
    float e = __expf(2.f * x);
    return 1.f - 2.f / (e + 1.f);
}
__device__ __forceinline__ ushort bf16rn(float x) {
    unsigned u = __float_as_uint(x);
    return (ushort)((u + 0x7fffu + ((u >> 16) & 1u)) >> 16);
}
__device__ __forceinline__ void split2(float x, ushort& h, ushort& l) {
    h = bf16rn(x);
    float hf = __uint_as_float(((unsigned)h) << 16);
    l = bf16rn(x - hf);
}

union FU { u32x4 uv; unsigned u[4]; ushort s[8]; bf16x8 v; };

// 16 waves/block, 4 elements (rows 0-11 real, 12-15 ghost pad); grid 256 (1 block/CU).
// Roles: w<8 = GEMM1 (2 N-tiles each); w 8-11 = GEMM2 owner (full K=256, holds state);
// w 12-15 = decoder (hidden in owner windows). 2 barriers per ODE eval.
// amdgpu_waves_per_eu(4,4): exactly 4 waves/EU -> VGPR budget 512/4 = 128.
// (hipcc's heuristic gives 1024-thr blocks only 64 VGPRs otherwise -> owner spill, r10.)
__global__ __attribute__((amdgpu_flat_work_group_size(1024, 1024), amdgpu_waves_per_eu(4, 4)))
void node_mfma11(const float* __restrict__ x,
                 const float* __restrict__ iw1, const float* __restrict__ ib1,
                 const float* __restrict__ iw2, const float* __restrict__ ib2,
                 const float* __restrict__ ow1, const float* __restrict__ ob1,
                 const float* __restrict__ ow2, const float* __restrict__ ob2,
                 const float* __restrict__ inter, const float* __restrict__ cons,
                 const float* __restrict__ dw1, const float* __restrict__ db1,
                 const float* __restrict__ dw2, const float* __restrict__ db2,
                 const float* __restrict__ tpts,
                 float* __restrict__ out)
{
    extern __shared__ float sm[];
    unsigned* YPw = (unsigned*)(sm + OFF_YP);   // hi [16][32]; lo at +512
    unsigned* TPw = (unsigned*)(sm + OFF_TP);   // hi [16][128]; lo at +2048
    float*    Yf  = sm + OFF_YF;
    float*    PS  = sm + OFF_PS;
    float*    tps = sm + OFF_TPS;
    float*    DW1 = sm + OFF_DW1;
    float*    DW2 = sm + OFF_DW2;
    float*    DB1 = sm + OFF_DB1;
    float*    DB2 = sm + OFF_DB2;

    const int tid = threadIdx.x;
    const int w   = tid >> 6;       // wave 0..15
    const int ln  = tid & 63;
    const int m   = ln & 15;
    const int g4  = ln >> 4;
    const bool isG1  = (w < 8);
    const bool isOwn = (w >= 8) && (w < 12);
    const bool isDec = (w >= 12);
    const int ntw = w - 8;          // owner tile
    const int del = w - 12;         // decoder element

    // ---- stage decode weights + t into LDS ----
    for (int idx = tid; idx < 3*HD*HD; idx += 1024) DW1[idx] = dw1[idx];
    if (tid < 3*HD)  { for (int v = 0; v < NV; ++v) DW2[tid*NV + v] = dw2[tid*NV + v]; }
    if (tid < 192)   DB1[tid] = db1[tid];
    if (tid < 21)    DB2[tid] = db2[tid];
    if (tid < TPTS)  tps[tid] = tpts[tid];

    // ---- role-specific weight fragments (overlaid register arrays) ----
    FU fh[8], fl[8];
    float w64c[2] = {0,0}, w65c[2] = {0,0}, b1c[2] = {0,0};
    float b2c = 0.f;
    if (isG1) {
        #pragma unroll
        for (int u = 0; u < 2; ++u) {
            const int c1 = 16*(2*w + u) + m;
            #pragma unroll
            for (int cc = 0; cc < 2; ++cc)
                #pragma unroll
                for (int j = 0; j < 8; ++j) {
                    ushort h, l;
                    split2(ow1[(32*cc + 8*g4 + j)*NH + c1], h, l);
                    fh[2*u + cc].s[j] = h; fl[2*u + cc].s[j] = l;
                }
            w64c[u] = ow1[64*NH + c1];
            w65c[u] = ow1[65*NH + c1];
            b1c[u]  = ob1[c1];
        }
    } else if (isOwn) {
        #pragma unroll
        for (int cc = 0; cc < 8; ++cc)
            #pragma unroll
            for (int j = 0; j < 8; ++j) {
                ushort h, l;
                split2(ow2[(32*cc + 8*g4 + j)*HD + 16*ntw + m], h, l);
                fh[cc].s[j] = h; fl[cc].s[j] = l;
            }
        b2c = ob2[16*ntw + m];
    }

    // M = conservation @ interaction, scaled 1/64 (G1 epilogue only)
    const int cpm = m % 3, base3 = m - cpm;
    float Mr0, Mr1, Mr2;
    {
        float I[9], C[9];
        #pragma unroll
        for (int i = 0; i < 9; ++i) { I[i] = inter[i]; C[i] = cons[i]; }
        float M_[3][3];
        #pragma unroll
        for (int r = 0; r < 3; ++r)
            #pragma unroll
            for (int c = 0; c < 3; ++c)
                M_[r][c] = (C[r*3+0]*I[0*3+c] + C[r*3+1]*I[1*3+c] + C[r*3+2]*I[2*3+c]) * (1.f/64.f);
        Mr0 = (cpm==0) ? M_[0][0] : (cpm==1) ? M_[1][0] : M_[2][0];
        Mr1 = (cpm==0) ? M_[0][1] : (cpm==1) ? M_[1][1] : M_[2][1];
        Mr2 = (cpm==0) ? M_[0][2] : (cpm==1) ? M_[1][2] : M_[2][2];
    }

    // ---- initial state y0 (each element redundantly by its wave group) ----
    {
        const int el0 = w >> 2;
        const int b0  = blockIdx.x*4 + el0;
        float xs0,xs1,xs2,xs3,xs4,xs5,xs6;
        {
            const float* xp = x + (size_t)b0 * TPTS * NV + ln * NV;
            float v0=xp[0],v1=xp[1],v2=xp[2],v3=xp[3],v4=xp[4],v5=xp[5],v6=xp[6];
            if (ln < 32) {
                const float* xp2 = xp + 64 * NV;
                v0+=xp2[0]; v1+=xp2[1]; v2+=xp2[2]; v3+=xp2[3]; v4+=xp2[4]; v5+=xp2[5]; v6+=xp2[6];
            }
            xs0=wsum64(v0)*(1.f/96.f); xs1=wsum64(v1)*(1.f/96.f); xs2=wsum64(v2)*(1.f/96.f);
            xs3=wsum64(v3)*(1.f/96.f); xs4=wsum64(v4)*(1.f/96.f); xs5=wsum64(v5)*(1.f/96.f);
            xs6=wsum64(v6)*(1.f/96.f);
        }
        float h0v;
        {
            float a = ib1[ln];
            a = fmaf(xs0, iw1[0*HD+ln], a); a = fmaf(xs1, iw1[1*HD+ln], a);
            a = fmaf(xs2, iw1[2*HD+ln], a); a = fmaf(xs3, iw1[3*HD+ln], a);
            a = fmaf(xs4, iw1[4*HD+ln], a); a = fmaf(xs5, iw1[5*HD+ln], a);
            a = fmaf(xs6, iw1[6*HD+ln], a);
            h0v = fmaxf(a, 0.f);
        }
        float y0a = ib2[ln], y0b = ib2[64+ln], y0c = ib2[128+ln];
        #pragma unroll
        for (int k = 0; k < 64; ++k) {
            float hk = rdlane(h0v, k);
            y0a = fmaf(hk, iw2[k*192 + ln],       y0a);
            y0b = fmaf(hk, iw2[k*192 + 64 + ln],  y0b);
            y0c = fmaf(hk, iw2[k*192 + 128 + ln], y0c);
        }
        if ((w & 3) == 0) {           // waves 0,4,8,12 publish element el0
            float yv[3] = {y0a, y0b, y0c};
            #pragma unroll
            for (int r = 0; r < 3; ++r) {
                int row = el0*3 + r;
                Yf[row*65 + ln] = yv[r];
                ushort hs, ls; split2(yv[r], hs, ls);
                unsigned hp = hs, lp = ls;
                unsigned hq = __shfl_xor(hp, 1), lq = __shfl_xor(lp, 1);
                if ((ln & 1) == 0) {
                    int wgrp = ln >> 3;
                    int woff = row*32 + ((((unsigned)(wgrp ^ row)) & 7) << 2) + ((ln >> 1) & 3);
                    YPw[woff]       = hp | (hq << 16);
                    YPw[512 + woff] = lp | (lq << 16);
                }
            }
            float S0 = wsum64(y0a), S1 = wsum64(y0b), S2 = wsum64(y0c);
            if (ln < 3) PS[el0*3 + ln] = (ln==0)?S0:(ln==1)?S1:S2;
        }
        if (w == 1 && ln < 48) PS[16 + ln] = 0.f;        // slots 1-3
        if (w == 3 && ln >= 12 && ln < 16) PS[ln] = 0.f; // slot 0 pad rows
        if (w == 2) {                                     // zero pad rows 12-15 of Y planes
            YPw[384 + ln] = 0u; YPw[448 + ln] = 0u;
            YPw[896 + ln] = 0u; YPw[960 + ln] = 0u;
        }
        if (w == 5) {                                     // zero pad rows 12-15 of Yf
            #pragma unroll
            for (int r = 12; r < 16; ++r) Yf[r*65 + ln] = 0.f;
        }
    }
    __syncthreads();

    // owners load state fragments from Yf
    f32x4 yb = {0,0,0,0}, ks = {0,0,0,0};
    if (isOwn) {
        #pragma unroll
        for (int r = 0; r < 4; ++r) yb[r] = Yf[(4*g4 + r)*65 + 16*ntw + m];
    }
    // decoder persistent accumulators
    float dacc[3] = {0,0,0}, dyv[3] = {0,0,0};

    // ---- GEMM1 phase (waves 0-7): 2 N-tiles, epilogue, T publish ----
    auto g1 = [&](float ts) {
        float rsum = (PS[m] + PS[16+m]) + (PS[32+m] + PS[48+m]);
        float eAll = Mr0*__shfl(rsum, base3) + Mr1*__shfl(rsum, base3+1) + Mr2*__shfl(rsum, base3+2);
        f32x4 aA0={0,0,0,0}, aB0={0,0,0,0}, aA1={0,0,0,0}, aB1={0,0,0,0};
        #pragma unroll
        for (int cc = 0; cc < 2; ++cc) {
            FU ah, al;
            int aoff = m*32 + ((((unsigned)((4*cc + g4) ^ m)) & 7) << 2);
            ah.uv = *(const u32x4*)(YPw + aoff);
            al.uv = *(const u32x4*)(YPw + 512 + aoff);
            aA0 = MFMA16(ah.v, fh[cc].v,   aA0);
            aB0 = MFMA16(ah.v, fl[cc].v,   aB0);
            aA0 = MFMA16(al.v, fh[cc].v,   aA0);
            aA1 = MFMA16(ah.v, fh[2+cc].v, aA1);
            aB1 = MFMA16(ah.v, fl[2+cc].v, aB1);
            aA1 = MFMA16(al.v, fh[2+cc].v, aA1);
        }
        #pragma unroll
        for (int r = 0; r < 4; ++r) {
            const int row = 4*g4 + r;
            float er = __shfl(eAll, row);
            #pragma unroll
            for (int u = 0; u < 2; ++u) {
                float val = u ? (aA1[r] + aB1[r]) : (aA0[r] + aB0[r]);
                val = fmaf(w64c[u], er, val);
                val = fmaf(w65c[u], ts, val);
                val += b1c[u];
                float th = tanh_fast(val);
                ushort hs, ls; split2(th, hs, ls);
                unsigned hp = hs, lp = ls;
                unsigned hq = __shfl_xor(hp, 1), lq = __shfl_xor(lp, 1);
                if ((m & 1) == 0) {
                    int wgrp = 4*w + 2*u + (m >> 3);
                    int woff = row*128 + ((((unsigned)wgrp & 24) | (((unsigned)(wgrp ^ row)) & 7)) << 2)
                             + ((m >> 1) & 3);
                    TPw[woff]        = hp | (hq << 16);
                    TPw[2048 + woff] = lp | (lq << 16);
                }
            }
        }
    };

    // ---- owner GEMM2: full K=256 for tile ntw ----
    auto g2 = [&]() -> f32x4 {
        f32x4 pA = {0,0,0,0}, pB = {0,0,0,0};
        #pragma unroll
        for (int cc = 0; cc < 8; ++cc) {
            FU ah, al;
            int G = 4*cc + g4;
            int aoff = m*128 + ((((unsigned)G & 24) | (((unsigned)(G ^ m)) & 7)) << 2);
            ah.uv = *(const u32x4*)(TPw + aoff);
            al.uv = *(const u32x4*)(TPw + 2048 + aoff);
            pA = MFMA16(ah.v, fh[cc].v, pA);
            pB = MFMA16(ah.v, fl[cc].v, pB);
            pA = MFMA16(al.v, fh[cc].v, pA);
        }
        f32x4 dd = pA + pB;
        dd[0] += b2c; dd[1] += b2c; dd[2] += b2c; dd[3] += b2c;
        return dd;
    };

    // ---- owner publish: 4 rows of Y planes + PS (+Yf on commit) ----
    auto opub = [&](f32x4 ys, bool commit) {
        #pragma unroll
        for (int r = 0; r < 4; ++r) {
            const int row = 4*g4 + r;
            ushort hs, ls; split2(ys[r], hs, ls);
            unsigned hp = hs, lp = ls;
            unsigned hq = __shfl_xor(hp, 1), lq = __shfl_xor(lp, 1);
            if ((m & 1) == 0) {
                int wgrp = 2*ntw + (m >> 3);
                int woff = row*32 + ((((unsigned)(wgrp ^ row)) & 7) << 2) + ((m >> 1) & 3);
                YPw[woff]       = hp | (hq << 16);
                YPw[512 + woff] = lp | (lq << 16);
            }
            if (commit) Yf[row*65 + 16*ntw + m] = ys[r];
        }
        float s0 = ys[0], s1 = ys[1], s2 = ys[2], s3 = ys[3];
        #pragma unroll
        for (int d = 1; d < 16; d <<= 1) {
            s0 += __shfl_xor(s0, d); s1 += __shfl_xor(s1, d);
            s2 += __shfl_xor(s2, d); s3 += __shfl_xor(s3, d);
        }
        float sv = (m==0)?s0:(m==1)?s1:(m==2)?s2:s3;
        if (m < 4) PS[ntw*16 + 4*g4 + m] = sv;
    };

    // ---- decoder work, split across the 4 owner windows of a step ----
    auto dwork = [&](int stage, int tix) {
        if (stage == 0) {
            #pragma unroll
            for (int cc = 0; cc < 3; ++cc) {
                dyv[cc]  = Yf[(3*del + cc)*65 + ln];
                dacc[cc] = DB1[cc*HD + ln];
            }
            #pragma unroll
            for (int h = 0; h < 21; ++h)
                #pragma unroll
                for (int cc = 0; cc < 3; ++cc)
                    dacc[cc] = fmaf(rdlane(dyv[cc], h), DW1[(cc*HD + h)*HD + ln], dacc[cc]);
        } else if (stage == 1) {
            #pragma unroll
            for (int h = 21; h < 42; ++h)
                #pragma unroll
                for (int cc = 0; cc < 3; ++cc)
                    dacc[cc] = fmaf(rdlane(dyv[cc], h), DW1[(cc*HD + h)*HD + ln], dacc[cc]);
        } else if (stage == 2) {
            #pragma unroll
            for (int h = 42; h < 64; ++h)
                #pragma unroll
                for (int cc = 0; cc < 3; ++cc)
                    dacc[cc] = fmaf(rdlane(dyv[cc], h), DW1[(cc*HD + h)*HD + ln], dacc[cc]);
        } else {
            const int b = blockIdx.x*4 + del;
            #pragma unroll
            for (int cc = 0; cc < 3; ++cc) {
                float hid = fmaxf(dacc[cc], 0.f);
                #pragma unroll
                for (int v = 0; v < NV; ++v) {
                    float pv = wsum64(hid * DW2[(cc*HD + ln)*NV + v]);
                    if (ln == 0)
                        out[(((size_t)cc*BTOT + b)*TPTS + tix)*NV + v] = pv + DB2[cc*NV + v];
                }
            }
        }
    };

    // ---- RK4 over 95 intervals; decode(s) runs inside step s's owner windows ----
    #pragma unroll 1
    for (int s = 0; s < TPTS - 1; ++s) {
        const float ta = tps[s], tb = tps[s + 1];
        const float dt = tb - ta, hdt = 0.5f * dt;

        // eval 1
        if (isG1) g1(ta);
        __syncthreads();
        if (isOwn) { f32x4 dd = g2(); ks = dd; opub(yb + hdt*dd, false); }
        else if (isDec) dwork(0, s);
        __syncthreads();

        // eval 2
        if (isG1) g1(ta + hdt);
        __syncthreads();
        if (isOwn) { f32x4 dd = g2(); ks += 2.f*dd; opub(yb + hdt*dd, false); }
        else if (isDec) dwork(1, s);
        __syncthreads();

        // eval 3
        if (isG1) g1(ta + hdt);
        __syncthreads();
        if (isOwn) { f32x4 dd = g2(); ks += 2.f*dd; opub(yb + dt*dd, false); }
        else if (isDec) dwork(2, s);
        __syncthreads();

        // eval 4 (commit)
        if (isG1) g1(tb);
        __syncthreads();
        if (isOwn) { f32x4 dd = g2(); ks += dd; yb = yb + (dt*(1.f/6.f))*ks; opub(yb, true); }
        else if (isDec) dwork(3, s);
        __syncthreads();
    }

    // tail: decode the final committed state (tix = 95)
    if (isDec) { dwork(0, TPTS-1); dwork(1, TPTS-1); dwork(2, TPTS-1); dwork(3, TPTS-1); }
}

extern "C" void kernel_launch(void* const* d_in, const int* in_sizes, int n_in,
                              void* d_out, int out_size, void* d_ws, size_t ws_size,
                              hipStream_t stream) {
    const float* x     = (const float*)d_in[0];
    const float* iw1   = (const float*)d_in[1];
    const float* ib1   = (const float*)d_in[2];
    const float* iw2   = (const float*)d_in[3];
    const float* ib2   = (const float*)d_in[4];
    const float* ow1   = (const float*)d_in[5];
    const float* ob1   = (const float*)d_in[6];
    const float* ow2   = (const float*)d_in[7];
    const float* ob2   = (const float*)d_in[8];
    const float* inter = (const float*)d_in[9];
    const float* cons  = (const float*)d_in[10];
    const float* dw1   = (const float*)d_in[11];
    const float* db1   = (const float*)d_in[12];
    const float* dw2   = (const float*)d_in[13];
    const float* db2   = (const float*)d_in[14];
    const float* tpts  = (const float*)d_in[15];
    float* out = (float*)d_out;

    // dynamic LDS > 64 KB (host-side, graph-capture safe)
    (void)hipFuncSetAttribute((const void*)node_mfma11,
                              hipFuncAttributeMaxDynamicSharedMemorySize,
                              SMEM_BYTES);

    node_mfma11<<<BTOT / 4, 1024, SMEM_BYTES, stream>>>(
        x, iw1, ib1, iw2, ib2, ow1, ob1, ow2, ob2,
        inter, cons, dw1, db1, dw2, db2, tpts, out);
}

// Round 12
// 1785.832 us; speedup vs baseline: 1.1015x; 1.1015x over previous
//
#include <hip/hip_runtime.h>

// Problem constants
#define BTOT 1024
#define TPTS 96
#define NV   7
#define HD   64
#define NH   256

typedef short bf16x8 __attribute__((ext_vector_type(8)));
typedef float f32x4  __attribute__((ext_vector_type(4)));
typedef unsigned int u32x4 __attribute__((ext_vector_type(4)));
#define MFMA16(a,b,c) __builtin_amdgcn_mfma_f32_16x16x32_bf16(a,b,c,0,0,0)

// LDS layout (32-bit word offsets), total 36560 words = 146240 B (1 block/CU)
#define OFF_YP   0        // 2 planes x [16 rows][32 words], XOR-swizzled   = 1024
#define OFF_TP   1024     // 2 planes x [16 rows][128 words], XOR-swizzled  = 4096
#define OFF_W2P  5120     // W2 bf16 planes hi[64 o][128 w] + lo, swizzled  = 16384
#define OFF_YF   21504    // f32 [16][65]                                   = 1040
#define OFF_PS   22544    // f32 [4 nt][16 rows] row-sum partials           = 64
#define OFF_TPS  22608    // 96
#define OFF_DW1  22704    // f32 [3][64][64]                                = 12288
#define OFF_DW2  34992    // f32 [3][64][7]                                 = 1344
#define OFF_DB1  36336    // 192
#define OFF_DB2  36528    // 32 (21 used)
#define SMEM_WORDS 36560
#define SMEM_BYTES (SMEM_WORDS*4)

__device__ __forceinline__ float rdlane(float v, int i) {
    return __int_as_float(__builtin_amdgcn_readlane(__float_as_int(v), i));
}
__device__ __forceinline__ float wsum64(float v) {
    v += __shfl_xor(v, 1);  v += __shfl_xor(v, 2);  v += __shfl_xor(v, 4);
    v += __shfl_xor(v, 8);  v += __shfl_xor(v, 16); v += __shfl_xor(v, 32);
    return v;
}
__device__ __forceinline__ float tanh_fast(float x) {
    float e = __expf(2.f * x);
    return 1.f - 2.f / (e + 1.f);
}
__device__ __forceinline__ ushort bf16rn(float x) {
    unsigned u = __float_as_uint(x);
    return (ushort)((u + 0x7fffu + ((u >> 16) & 1u)) >> 16);
}
// 2-term round-to-nearest bf16 decomposition: x ~= h + l, error ~2^-18 rel
__device__ __forceinline__ void split2(float x, ushort& h, ushort& l) {
    h = bf16rn(x);
    float hf = __uint_as_float(((unsigned)h) << 16);
    l = bf16rn(x - hf);
}

union FU { u32x4 uv; unsigned u[4]; ushort s[8]; bf16x8 v; };

// 16 waves/block, 4 elements (rows 0-11 real, 12-15 ghost pad); grid 256 (1 block/CU).
// Roles: w<8 = GEMM1 (2 N-tiles each, W1 frags in registers, 32 VGPR);
//        w 8-11 = GEMM2 owner (full K=256; A from T planes, B STREAMED from LDS W2
//                 planes -> no big register arrays, fits the 64-VGPR cap of 1024-thr blocks);
//        w 12-15 = decoder (element w-12, hidden inside owner windows).
// 2 barriers per ODE eval. (r10/r11 spilled because owners held 64 VGPRs of W2 frags.)
__global__ __launch_bounds__(1024, 1)
void node_mfma12(const float* __restrict__ x,
                 const float* __restrict__ iw1, const float* __restrict__ ib1,
                 const float* __restrict__ iw2, const float* __restrict__ ib2,
                 const float* __restrict__ ow1, const float* __restrict__ ob1,
                 const float* __restrict__ ow2, const float* __restrict__ ob2,
                 const float* __restrict__ inter, const float* __restrict__ cons,
                 const float* __restrict__ dw1, const float* __restrict__ db1,
                 const float* __restrict__ dw2, const float* __restrict__ db2,
                 const float* __restrict__ tpts,
                 float* __restrict__ out)
{
    extern __shared__ float sm[];
    unsigned* YPw  = (unsigned*)(sm + OFF_YP);   // hi [16][32]; lo at +512
    unsigned* TPw  = (unsigned*)(sm + OFF_TP);   // hi [16][128]; lo at +2048
    unsigned* W2Pw = (unsigned*)(sm + OFF_W2P);  // hi [64][128]; lo at +8192
    float*    Yf  = sm + OFF_YF;
    float*    PS  = sm + OFF_PS;
    float*    tps = sm + OFF_TPS;
    float*    DW1 = sm + OFF_DW1;
    float*    DW2 = sm + OFF_DW2;
    float*    DB1 = sm + OFF_DB1;
    float*    DB2 = sm + OFF_DB2;

    const int tid = threadIdx.x;
    const int w   = tid >> 6;       // wave 0..15
    const int ln  = tid & 63;
    const int m   = ln & 15;
    const int g4  = ln >> 6 == 0 ? (ln >> 4) : (ln >> 4);   // quad 0..3
    const bool isG1  = (w < 8);
    const bool isOwn = (w >= 8) && (w < 12);
    const bool isDec = (w >= 12);
    const int ntw = w - 8;          // owner tile
    const int del = w - 12;         // decoder element

    // ---- stage decode weights + t into LDS ----
    for (int idx = tid; idx < 3*HD*HD; idx += 1024) DW1[idx] = dw1[idx];
    if (tid < 3*HD)  { for (int v = 0; v < NV; ++v) DW2[tid*NV + v] = dw2[tid*NV + v]; }
    if (tid < 192)   DB1[tid] = db1[tid];
    if (tid < 21)    DB2[tid] = db2[tid];
    if (tid < TPTS)  tps[tid] = tpts[tid];

    // ---- stage W2 hi/lo bf16 planes, swizzled: granule gi=k>>3 XORed with (o&31) ----
    {
        ushort* W2H = (ushort*)W2Pw;
        ushort* W2L = (ushort*)(W2Pw + 8192);
        for (int idx = tid; idx < NH*HD; idx += 1024) {
            int k = idx >> 6, o = idx & 63;              // ow2[k][o]
            ushort h, l; split2(ow2[idx], h, l);
            int gi = k >> 3;
            int word = o*128 + ((((unsigned)(gi ^ (o & 31))) & 31) << 2) + ((k >> 1) & 3);
            int us   = word*2 + (k & 1);
            W2H[us] = h; W2L[us] = l;
        }
    }

    // ---- G1 weight fragments in registers (32 VGPR) ----
    FU fh[4], fl[4];
    float w64c[2] = {0,0}, w65c[2] = {0,0}, b1c[2] = {0,0};
    float b2c = 0.f;
    if (isG1) {
        #pragma unroll
        for (int u = 0; u < 2; ++u) {
            const int c1 = 16*(2*w + u) + m;
            #pragma unroll
            for (int cc = 0; cc < 2; ++cc)
                #pragma unroll
                for (int j = 0; j < 8; ++j) {
                    ushort h, l;
                    split2(ow1[(32*cc + 8*g4 + j)*NH + c1], h, l);
                    fh[2*u + cc].s[j] = h; fl[2*u + cc].s[j] = l;
                }
            w64c[u] = ow1[64*NH + c1];
            w65c[u] = ow1[65*NH + c1];
            b1c[u]  = ob1[c1];
        }
    } else if (isOwn) {
        b2c = ob2[16*ntw + m];
    }

    // M = conservation @ interaction, scaled 1/64 (G1 epilogue only)
    const int cpm = m % 3, base3 = m - cpm;
    float Mr0, Mr1, Mr2;
    {
        float I[9], C[9];
        #pragma unroll
        for (int i = 0; i < 9; ++i) { I[i] = inter[i]; C[i] = cons[i]; }
        float M_[3][3];
        #pragma unroll
        for (int r = 0; r < 3; ++r)
            #pragma unroll
            for (int c = 0; c < 3; ++c)
                M_[r][c] = (C[r*3+0]*I[0*3+c] + C[r*3+1]*I[1*3+c] + C[r*3+2]*I[2*3+c]) * (1.f/64.f);
        Mr0 = (cpm==0) ? M_[0][0] : (cpm==1) ? M_[1][0] : M_[2][0];
        Mr1 = (cpm==0) ? M_[0][1] : (cpm==1) ? M_[1][1] : M_[2][1];
        Mr2 = (cpm==0) ? M_[0][2] : (cpm==1) ? M_[1][2] : M_[2][2];
    }

    // ---- initial state y0 (each element redundantly by its wave group) ----
    {
        const int el0 = w >> 2;
        const int b0  = blockIdx.x*4 + el0;
        float xs0,xs1,xs2,xs3,xs4,xs5,xs6;
        {
            const float* xp = x + (size_t)b0 * TPTS * NV + ln * NV;
            float v0=xp[0],v1=xp[1],v2=xp[2],v3=xp[3],v4=xp[4],v5=xp[5],v6=xp[6];
            if (ln < 32) {
                const float* xp2 = xp + 64 * NV;
                v0+=xp2[0]; v1+=xp2[1]; v2+=xp2[2]; v3+=xp2[3]; v4+=xp2[4]; v5+=xp2[5]; v6+=xp2[6];
            }
            xs0=wsum64(v0)*(1.f/96.f); xs1=wsum64(v1)*(1.f/96.f); xs2=wsum64(v2)*(1.f/96.f);
            xs3=wsum64(v3)*(1.f/96.f); xs4=wsum64(v4)*(1.f/96.f); xs5=wsum64(v5)*(1.f/96.f);
            xs6=wsum64(v6)*(1.f/96.f);
        }
        float h0v;
        {
            float a = ib1[ln];
            a = fmaf(xs0, iw1[0*HD+ln], a); a = fmaf(xs1, iw1[1*HD+ln], a);
            a = fmaf(xs2, iw1[2*HD+ln], a); a = fmaf(xs3, iw1[3*HD+ln], a);
            a = fmaf(xs4, iw1[4*HD+ln], a); a = fmaf(xs5, iw1[5*HD+ln], a);
            a = fmaf(xs6, iw1[6*HD+ln], a);
            h0v = fmaxf(a, 0.f);
        }
        float y0a = ib2[ln], y0b = ib2[64+ln], y0c = ib2[128+ln];
        #pragma unroll
        for (int k = 0; k < 64; ++k) {
            float hk = rdlane(h0v, k);
            y0a = fmaf(hk, iw2[k*192 + ln],       y0a);
            y0b = fmaf(hk, iw2[k*192 + 64 + ln],  y0b);
            y0c = fmaf(hk, iw2[k*192 + 128 + ln], y0c);
        }
        if ((w & 3) == 0) {           // waves 0,4,8,12 publish element el0
            float yv[3] = {y0a, y0b, y0c};
            #pragma unroll
            for (int r = 0; r < 3; ++r) {
                int row = el0*3 + r;
                Yf[row*65 + ln] = yv[r];
                ushort hs, ls; split2(yv[r], hs, ls);
                unsigned hp = hs, lp = ls;
                unsigned hq = __shfl_xor(hp, 1), lq = __shfl_xor(lp, 1);
                if ((ln & 1) == 0) {
                    int wgrp = ln >> 3;
                    int woff = row*32 + ((((unsigned)(wgrp ^ row)) & 7) << 2) + ((ln >> 1) & 3);
                    YPw[woff]       = hp | (hq << 16);
                    YPw[512 + woff] = lp | (lq << 16);
                }
            }
            float S0 = wsum64(y0a), S1 = wsum64(y0b), S2 = wsum64(y0c);
            if (ln < 3) PS[el0*3 + ln] = (ln==0)?S0:(ln==1)?S1:S2;
        }
        if (w == 1 && ln < 48) PS[16 + ln] = 0.f;        // slots 1-3
        if (w == 3 && ln >= 12 && ln < 16) PS[ln] = 0.f; // slot 0 pad rows
        if (w == 2) {                                     // zero pad rows 12-15 of Y planes
            YPw[384 + ln] = 0u; YPw[448 + ln] = 0u;
            YPw[896 + ln] = 0u; YPw[960 + ln] = 0u;
        }
        if (w == 5) {                                     // zero pad rows 12-15 of Yf
            #pragma unroll
            for (int r = 12; r < 16; ++r) Yf[r*65 + ln] = 0.f;
        }
    }
    __syncthreads();

    // owners load state fragments from Yf
    f32x4 yb = {0,0,0,0}, ks = {0,0,0,0};
    if (isOwn) {
        #pragma unroll
        for (int r = 0; r < 4; ++r) yb[r] = Yf[(4*g4 + r)*65 + 16*ntw + m];
    }
    // decoder persistent accumulators
    float dacc[3] = {0,0,0}, dyv[3] = {0,0,0};

    // ---- GEMM1 phase (waves 0-7): 2 N-tiles, epilogue, T publish ----
    auto g1 = [&](float ts) {
        float rsum = (PS[m] + PS[16+m]) + (PS[32+m] + PS[48+m]);
        float eAll = Mr0*__shfl(rsum, base3) + Mr1*__shfl(rsum, base3+1) + Mr2*__shfl(rsum, base3+2);
        f32x4 aA0={0,0,0,0}, aB0={0,0,0,0}, aA1={0,0,0,0}, aB1={0,0,0,0};
        #pragma unroll
        for (int cc = 0; cc < 2; ++cc) {
            FU ah, al;
            int aoff = m*32 + ((((unsigned)((4*cc + g4) ^ m)) & 7) << 2);
            ah.uv = *(const u32x4*)(YPw + aoff);
            al.uv = *(const u32x4*)(YPw + 512 + aoff);
            aA0 = MFMA16(ah.v, fh[cc].v,   aA0);
            aB0 = MFMA16(ah.v, fl[cc].v,   aB0);
            aA0 = MFMA16(al.v, fh[cc].v,   aA0);
            aA1 = MFMA16(ah.v, fh[2+cc].v, aA1);
            aB1 = MFMA16(ah.v, fl[2+cc].v, aB1);
            aA1 = MFMA16(al.v, fh[2+cc].v, aA1);
        }
        #pragma unroll
        for (int r = 0; r < 4; ++r) {
            const int row = 4*g4 + r;
            float er = __shfl(eAll, row);
            #pragma unroll
            for (int u = 0; u < 2; ++u) {
                float val = u ? (aA1[r] + aB1[r]) : (aA0[r] + aB0[r]);
                val = fmaf(w64c[u], er, val);
                val = fmaf(w65c[u], ts, val);
                val += b1c[u];
                float th = tanh_fast(val);
                ushort hs, ls; split2(th, hs, ls);
                unsigned hp = hs, lp = ls;
                unsigned hq = __shfl_xor(hp, 1), lq = __shfl_xor(lp, 1);
                if ((m & 1) == 0) {
                    int wgrp = 4*w + 2*u + (m >> 3);
                    int woff = row*128 + ((((unsigned)wgrp & 24) | (((unsigned)(wgrp ^ row)) & 7)) << 2)
                             + ((m >> 1) & 3);
                    TPw[woff]        = hp | (hq << 16);
                    TPw[2048 + woff] = lp | (lq << 16);
                }
            }
        }
    };

    // ---- owner GEMM2: full K=256, A from T planes, B streamed from W2 planes ----
    auto g2 = [&]() -> f32x4 {
        f32x4 pA = {0,0,0,0}, pB = {0,0,0,0};
        const int o = 16*ntw + m;
        #pragma unroll
        for (int cc = 0; cc < 8; ++cc) {
            FU ah, al, bh, bl;
            int G = 4*cc + g4;
            int aoff = m*128 + ((((unsigned)G & 24) | (((unsigned)(G ^ m)) & 7)) << 2);
            ah.uv = *(const u32x4*)(TPw + aoff);
            al.uv = *(const u32x4*)(TPw + 2048 + aoff);
            int woff = o*128 + ((((unsigned)(G ^ (o & 31))) & 31) << 2);
            bh.uv = *(const u32x4*)(W2Pw + woff);
            bl.uv = *(const u32x4*)(W2Pw + 8192 + woff);
            pA = MFMA16(ah.v, bh.v, pA);
            pB = MFMA16(ah.v, bl.v, pB);
            pA = MFMA16(al.v, bh.v, pA);
        }
        f32x4 dd = pA + pB;
        dd[0] += b2c; dd[1] += b2c; dd[2] += b2c; dd[3] += b2c;
        return dd;
    };

    // ---- owner publish: 4 rows of Y planes + PS (+Yf on commit) ----
    auto opub = [&](f32x4 ys, bool commit) {
        #pragma unroll
        for (int r = 0; r < 4; ++r) {
            const int row = 4*g4 + r;
            ushort hs, ls; split2(ys[r], hs, ls);
            unsigned hp = hs, lp = ls;
            unsigned hq = __shfl_xor(hp, 1), lq = __shfl_xor(lp, 1);
            if ((m & 1) == 0) {
                int wgrp = 2*ntw + (m >> 3);
                int woff = row*32 + ((((unsigned)(wgrp ^ row)) & 7) << 2) + ((m >> 1) & 3);
                YPw[woff]       = hp | (hq << 16);
                YPw[512 + woff] = lp | (lq << 16);
            }
            if (commit) Yf[row*65 + 16*ntw + m] = ys[r];
        }
        float s0 = ys[0], s1 = ys[1], s2 = ys[2], s3 = ys[3];
        #pragma unroll
        for (int d = 1; d < 16; d <<= 1) {
            s0 += __shfl_xor(s0, d); s1 += __shfl_xor(s1, d);
            s2 += __shfl_xor(s2, d); s3 += __shfl_xor(s3, d);
        }
        float sv = (m==0)?s0:(m==1)?s1:(m==2)?s2:s3;
        if (m < 4) PS[ntw*16 + 4*g4 + m] = sv;
    };

    // ---- decoder work, split across the 4 owner windows of a step ----
    auto dwork = [&](int stage, int tix) {
        if (stage == 0) {
            #pragma unroll
            for (int cc = 0; cc < 3; ++cc) {
                dyv[cc]  = Yf[(3*del + cc)*65 + ln];
                dacc[cc] = DB1[cc*HD + ln];
            }
            #pragma unroll
            for (int h = 0; h < 21; ++h)
                #pragma unroll
                for (int cc = 0; cc < 3; ++cc)
                    dacc[cc] = fmaf(rdlane(dyv[cc], h), DW1[(cc*HD + h)*HD + ln], dacc[cc]);
        } else if (stage == 1) {
            #pragma unroll
            for (int h = 21; h < 42; ++h)
                #pragma unroll
                for (int cc = 0; cc < 3; ++cc)
                    dacc[cc] = fmaf(rdlane(dyv[cc], h), DW1[(cc*HD + h)*HD + ln], dacc[cc]);
        } else if (stage == 2) {
            #pragma unroll
            for (int h = 42; h < 64; ++h)
                #pragma unroll
                for (int cc = 0; cc < 3; ++cc)
                    dacc[cc] = fmaf(rdlane(dyv[cc], h), DW1[(cc*HD + h)*HD + ln], dacc[cc]);
        } else {
            const int b = blockIdx.x*4 + del;
            #pragma unroll
            for (int cc = 0; cc < 3; ++cc) {
                float hid = fmaxf(dacc[cc], 0.f);
                #pragma unroll
                for (int v = 0; v < NV; ++v) {
                    float pv = wsum64(hid * DW2[(cc*HD + ln)*NV + v]);
                    if (ln == 0)
                        out[(((size_t)cc*BTOT + b)*TPTS + tix)*NV + v] = pv + DB2[cc*NV + v];
                }
            }
        }
    };

    // ---- RK4 over 95 intervals; decode(s) runs inside step s's owner windows ----
    #pragma unroll 1
    for (int s = 0; s < TPTS - 1; ++s) {
        const float ta = tps[s], tb = tps[s + 1];
        const float dt = tb - ta, hdt = 0.5f * dt;

        // eval 1
        if (isG1) g1(ta);
        __syncthreads();
        if (isOwn) { f32x4 dd = g2(); ks = dd; opub(yb + hdt*dd, false); }
        else if (isDec) dwork(0, s);
        __syncthreads();

        // eval 2
        if (isG1) g1(ta + hdt);
        __syncthreads();
        if (isOwn) { f32x4 dd = g2(); ks += 2.f*dd; opub(yb + hdt*dd, false); }
        else if (isDec) dwork(1, s);
        __syncthreads();

        // eval 3
        if (isG1) g1(ta + hdt);
        __syncthreads();
        if (isOwn) { f32x4 dd = g2(); ks += 2.f*dd; opub(yb + dt*dd, false); }
        else if (isDec) dwork(2, s);
        __syncthreads();

        // eval 4 (commit)
        if (isG1) g1(tb);
        __syncthreads();
        if (isOwn) { f32x4 dd = g2(); ks += dd; yb = yb + (dt*(1.f/6.f))*ks; opub(yb, true); }
        else if (isDec) dwork(3, s);
        __syncthreads();
    }

    // tail: decode the final committed state (tix = 95)
    if (isDec) { dwork(0, TPTS-1); dwork(1, TPTS-1); dwork(2, TPTS-1); dwork(3, TPTS-1); }
}

extern "C" void kernel_launch(void* const* d_in, const int* in_sizes, int n_in,
                              void* d_out, int out_size, void* d_ws, size_t ws_size,
                              hipStream_t stream) {
    const float* x     = (const float*)d_in[0];
    const float* iw1   = (const float*)d_in[1];
    const float* ib1   = (const float*)d_in[2];
    const float* iw2   = (const float*)d_in[3];
    const float* ib2   = (const float*)d_in[4];
    const float* ow1   = (const float*)d_in[5];
    const float* ob1   = (const float*)d_in[6];
    const float* ow2   = (const float*)d_in[7];
    const float* ob2   = (const float*)d_in[8];
    const float* inter = (const float*)d_in[9];
    const float* cons  = (const float*)d_in[10];
    const float* dw1   = (const float*)d_in[11];
    const float* db1   = (const float*)d_in[12];
    const float* dw2   = (const float*)d_in[13];
    const float* db2   = (const float*)d_in[14];
    const float* tpts  = (const float*)d_in[15];
    float* out = (float*)d_out;

    // dynamic LDS > 64 KB (host-side, graph-capture safe)
    (void)hipFuncSetAttribute((const void*)node_mfma12,
                              hipFuncAttributeMaxDynamicSharedMemorySize,
                              SMEM_BYTES);

    node_mfma12<<<BTOT / 4, 1024, SMEM_BYTES, stream>>>(
        x, iw1, ib1, iw2, ib2, ow1, ob1, ow2, ob2,
        inter, cons, dw1, db1, dw2, db2, tpts, out);
}

// Round 13
// 1325.597 us; speedup vs baseline: 1.4839x; 1.3472x over previous
//
#include <hip/hip_runtime.h>

// Problem constants
#define BTOT 1024
#define TPTS 96
#define NV   7
#define HD   64
#define NH   256

typedef short bf16x8 __attribute__((ext_vector_type(8)));
typedef float f32x4  __attribute__((ext_vector_type(4)));
typedef unsigned int u32x4 __attribute__((ext_vector_type(4)));
#define MFMA16(a,b,c) __builtin_amdgcn_mfma_f32_16x16x32_bf16(a,b,c,0,0,0)

// LDS layout (32-bit word offsets), total 22736 words = 90944 B (1 block/CU)
#define OFF_YP   0        // 2 planes x [16 rows][32 words], XOR-swizzled   = 1024
#define OFF_TP   1024     // 2 planes x [16 rows][128 words], XOR-swizzled  = 4096
#define OFF_PRT  5120     // 8 waves x [16 m][20] f32                       = 2560
#define OFF_YF   7680     // f32 [16][65] (decode only, commit writes)      = 1040
#define OFF_PS   8720     // f32 [4 nt][16 rows] row-sum partials           = 64
#define OFF_TPS  8784     // 96
#define OFF_DW1  8880     // f32 [3][64][64] decode layer-1                 = 12288
#define OFF_DW2  21168    // f32 [3][64][7]                                 = 1344
#define OFF_DB1  22512    // 192
#define OFF_DB2  22704    // 32 (21 used)
#define SMEM_WORDS 22736
#define SMEM_BYTES (SMEM_WORDS*4)

__device__ __forceinline__ float rdlane(float v, int i) {
    return __int_as_float(__builtin_amdgcn_readlane(__float_as_int(v), i));
}
__device__ __forceinline__ float wsum64(float v) {
    v += __shfl_xor(v, 1);  v += __shfl_xor(v, 2);  v += __shfl_xor(v, 4);
    v += __shfl_xor(v, 8);  v += __shfl_xor(v, 16); v += __shfl_xor(v, 32);
    return v;
}
__device__ __forceinline__ float tanh_fast(float x) {
    float e = __expf(2.f * x);
    return 1.f - 2.f / (e + 1.f);
}
__device__ __forceinline__ ushort bf16rn(float x) {
    unsigned u = __float_as_uint(x);
    return (ushort)((u + 0x7fffu + ((u >> 16) & 1u)) >> 16);
}
// 2-term round-to-nearest bf16 decomposition: x ~= h + l, error ~2^-18 rel
__device__ __forceinline__ void split2(float x, ushort& h, ushort& l) {
    h = bf16rn(x);
    float hf = __uint_as_float(((unsigned)h) << 16);
    l = bf16rn(x - hf);
}

union FU { u32x4 uv; unsigned u[4]; ushort s[8]; bf16x8 v; };

// 8 waves/block; 4 batch elements (rows 0-11 real, 12-15 ghost pad); grid 256.
// r9's proven 8-wave/124-VGPR engine with r7's 4-element geometry:
// GEMM1: wave w -> N-tiles {2w,2w+1} (A-reads amortized over 2 tiles).
// GEMM2: wave w -> (nt=w&3, K-half kh=w>>2), W2 frags in registers; PRT pair exchange.
// State replicated across all waves (per nt); publish sliced by kh (2 rows/thread).
// __launch_bounds__ 2nd arg = min BLOCKS/CU (CUDA semantics): 2 -> 128-VGPR cap, no spill.
__global__ __launch_bounds__(512, 2)
void node_mfma13(const float* __restrict__ x,
                 const float* __restrict__ iw1, const float* __restrict__ ib1,
                 const float* __restrict__ iw2, const float* __restrict__ ib2,
                 const float* __restrict__ ow1, const float* __restrict__ ob1,
                 const float* __restrict__ ow2, const float* __restrict__ ob2,
                 const float* __restrict__ inter, const float* __restrict__ cons,
                 const float* __restrict__ dw1, const float* __restrict__ db1,
                 const float* __restrict__ dw2, const float* __restrict__ db2,
                 const float* __restrict__ tpts,
                 float* __restrict__ out)
{
    extern __shared__ float sm[];
    unsigned* YPw = (unsigned*)(sm + OFF_YP);   // hi [16][32]; lo at +512
    unsigned* TPw = (unsigned*)(sm + OFF_TP);   // hi [16][128]; lo at +2048
    float*    PRT = sm + OFF_PRT;
    float*    Yf  = sm + OFF_YF;
    float*    PS  = sm + OFF_PS;
    float*    tps = sm + OFF_TPS;
    float*    DW1 = sm + OFF_DW1;
    float*    DW2 = sm + OFF_DW2;
    float*    DB1 = sm + OFF_DB1;
    float*    DB2 = sm + OFF_DB2;

    const int tid = threadIdx.x;
    const int w   = tid >> 6;       // wave 0..7
    const int ln  = tid & 63;
    const int m   = ln & 15;        // tile row/col index
    const int g4  = ln >> 4;        // quad 0..3
    const int nt  = w & 3;          // GEMM2 N-tile / state tile
    const int kh  = w >> 2;         // GEMM2 K-half / publish row-slice

    // ---- stage decode weights + t into LDS ----
    for (int idx = tid; idx < 3*HD*HD; idx += 512) DW1[idx] = dw1[idx];
    if (tid < 3*HD)  { for (int v = 0; v < NV; ++v) DW2[tid*NV + v] = dw2[tid*NV + v]; }
    if (tid < 192)   DB1[tid] = db1[tid];
    if (tid < 21)    DB2[tid] = db2[tid];
    if (tid < TPTS)  tps[tid] = tpts[tid];

    // ---- per-wave constant weight fragments in registers (r9-proven shapes) ----
    FU w1h[2][2], w1l[2][2];        // [tile u][cc]
    FU w2h[4], w2l[4];              // [cc] over K-half
    #pragma unroll
    for (int u = 0; u < 2; ++u)
        #pragma unroll
        for (int cc = 0; cc < 2; ++cc)
            #pragma unroll
            for (int j = 0; j < 8; ++j) {
                ushort h, l;
                int k1 = 32*cc + 8*g4 + j;
                split2(ow1[k1*NH + 16*(2*w+u) + m], h, l);
                w1h[u][cc].s[j] = h; w1l[u][cc].s[j] = l;
            }
    #pragma unroll
    for (int cc = 0; cc < 4; ++cc)
        #pragma unroll
        for (int j = 0; j < 8; ++j) {
            ushort h, l;
            int k2 = 128*kh + 32*cc + 8*g4 + j;
            split2(ow2[k2*HD + 16*nt + m], h, l);
            w2h[cc].s[j] = h; w2l[cc].s[j] = l;
        }
    float w64c[2], w65c[2], b1c[2];
    #pragma unroll
    for (int u = 0; u < 2; ++u) {
        int c1 = 16*(2*w+u) + m;
        w64c[u] = ow1[64*NH + c1];
        w65c[u] = ow1[65*NH + c1];
        b1c[u]  = ob1[c1];
    }
    const float b2c = ob2[16*nt + m];

    // M = conservation @ interaction, scaled 1/64; per-lane row cpm = m%3
    const int cpm = m % 3, base3 = m - cpm;
    float Mr0, Mr1, Mr2;
    {
        float I[9], C[9];
        #pragma unroll
        for (int i = 0; i < 9; ++i) { I[i] = inter[i]; C[i] = cons[i]; }
        float M_[3][3];
        #pragma unroll
        for (int r = 0; r < 3; ++r)
            #pragma unroll
            for (int c = 0; c < 3; ++c)
                M_[r][c] = (C[r*3+0]*I[0*3+c] + C[r*3+1]*I[1*3+c] + C[r*3+2]*I[2*3+c]) * (1.f/64.f);
        Mr0 = (cpm==0) ? M_[0][0] : (cpm==1) ? M_[1][0] : M_[2][0];
        Mr1 = (cpm==0) ? M_[0][1] : (cpm==1) ? M_[1][1] : M_[2][1];
        Mr2 = (cpm==0) ? M_[0][2] : (cpm==1) ? M_[1][2] : M_[2][2];
    }

    // ---- initial state y0: waves {2e,2e+1} redundantly compute element e ----
    {
        const int el0 = w >> 1;                 // 0..3
        const int b0  = blockIdx.x*4 + el0;
        float xs0,xs1,xs2,xs3,xs4,xs5,xs6;
        {
            const float* xp = x + (size_t)b0 * TPTS * NV + ln * NV;
            float v0=xp[0],v1=xp[1],v2=xp[2],v3=xp[3],v4=xp[4],v5=xp[5],v6=xp[6];
            if (ln < 32) {
                const float* xp2 = xp + 64 * NV;
                v0+=xp2[0]; v1+=xp2[1]; v2+=xp2[2]; v3+=xp2[3]; v4+=xp2[4]; v5+=xp2[5]; v6+=xp2[6];
            }
            xs0=wsum64(v0)*(1.f/96.f); xs1=wsum64(v1)*(1.f/96.f); xs2=wsum64(v2)*(1.f/96.f);
            xs3=wsum64(v3)*(1.f/96.f); xs4=wsum64(v4)*(1.f/96.f); xs5=wsum64(v5)*(1.f/96.f);
            xs6=wsum64(v6)*(1.f/96.f);
        }
        float h0v;
        {
            float a = ib1[ln];
            a = fmaf(xs0, iw1[0*HD+ln], a); a = fmaf(xs1, iw1[1*HD+ln], a);
            a = fmaf(xs2, iw1[2*HD+ln], a); a = fmaf(xs3, iw1[3*HD+ln], a);
            a = fmaf(xs4, iw1[4*HD+ln], a); a = fmaf(xs5, iw1[5*HD+ln], a);
            a = fmaf(xs6, iw1[6*HD+ln], a);
            h0v = fmaxf(a, 0.f);
        }
        float y0a = ib2[ln], y0b = ib2[64+ln], y0c = ib2[128+ln];
        #pragma unroll
        for (int k = 0; k < 64; ++k) {
            float hk = rdlane(h0v, k);
            y0a = fmaf(hk, iw2[k*192 + ln],       y0a);
            y0b = fmaf(hk, iw2[k*192 + 64 + ln],  y0b);
            y0c = fmaf(hk, iw2[k*192 + 128 + ln], y0c);
        }
        if ((w & 1) == 0) {           // waves 0,2,4,6: publish element el0 (rows 3el0..3el0+2)
            float yv[3] = {y0a, y0b, y0c};
            #pragma unroll
            for (int r = 0; r < 3; ++r) {
                int row = el0*3 + r;
                Yf[row*65 + ln] = yv[r];
                ushort hs, ls; split2(yv[r], hs, ls);
                unsigned hp = hs, lp = ls;
                unsigned hq = __shfl_xor(hp, 1), lq = __shfl_xor(lp, 1);
                if ((ln & 1) == 0) {
                    int wgrp = ln >> 3;
                    int woff = row*32 + ((((unsigned)(wgrp ^ row)) & 7) << 2) + ((ln >> 1) & 3);
                    YPw[woff]       = hp | (hq << 16);
                    YPw[512 + woff] = lp | (lq << 16);
                }
            }
            float S0 = wsum64(y0a), S1 = wsum64(y0b), S2 = wsum64(y0c);
            if (ln < 3) PS[el0*3 + ln] = (ln==0)?S0:(ln==1)?S1:S2;
        }
        if (w == 1 && ln < 48) PS[16 + ln] = 0.f;         // slots 1-3 fully zero
        if (w == 5 && ln >= 12 && ln < 16) PS[ln] = 0.f;  // slot 0 ghost rows
        if (w == 3) {                                      // zero ghost rows 12-15 of Y planes
            YPw[384 + ln] = 0u; YPw[448 + ln] = 0u;
            YPw[896 + ln] = 0u; YPw[960 + ln] = 0u;
        }
        if (w == 7) {                                      // zero ghost rows 12-15 of Yf
            #pragma unroll
            for (int r = 12; r < 16; ++r) Yf[r*65 + ln] = 0.f;
        }
    }
    __syncthreads();

    // state fragments, replicated in all waves (bitwise-identical per nt)
    f32x4 yb, ks;
    #pragma unroll
    for (int r = 0; r < 4; ++r) yb[r] = Yf[(4*g4 + r)*65 + 16*nt + m];

    // ---- publish (all waves): rows r = 2kh, 2kh+1 of this wave's fragment ----
    auto publish = [&](f32x4 ys, bool commit) {
        #pragma unroll
        for (int rr = 0; rr < 2; ++rr) {
            float yv = kh ? (rr ? ys[3] : ys[2]) : (rr ? ys[1] : ys[0]);
            const int row = 4*g4 + 2*kh + rr;
            ushort hs, ls; split2(yv, hs, ls);
            unsigned hp = hs, lp = ls;
            unsigned hq = __shfl_xor(hp, 1), lq = __shfl_xor(lp, 1);
            if ((m & 1) == 0) {
                int wgrp = 2*nt + (m >> 3);
                int woff = row*32 + ((((unsigned)(wgrp ^ row)) & 7) << 2) + ((m >> 1) & 3);
                YPw[woff]       = hp | (hq << 16);
                YPw[512 + woff] = lp | (lq << 16);
            }
            if (commit) Yf[row*65 + 16*nt + m] = yv;
            float s = yv;
            s += __shfl_xor(s, 1); s += __shfl_xor(s, 2);
            s += __shfl_xor(s, 4); s += __shfl_xor(s, 8);
            if (m == 0) PS[nt*16 + row] = s;
        }
    };

    // ---- one ODE-func eval (2 internal barriers; caller adds the third) ----
    auto evalf = [&](float ts, f32x4& dd) {
        // interaction effect from row-sum partials
        float rsum = (PS[m] + PS[16+m]) + (PS[32+m] + PS[48+m]);
        float eAll = Mr0*__shfl(rsum, base3) + Mr1*__shfl(rsum, base3+1) + Mr2*__shfl(rsum, base3+2);

        // GEMM1 (K=64), two N-tiles sharing the A-fragments
        f32x4 aA0 = {0,0,0,0}, aB0 = {0,0,0,0}, aA1 = {0,0,0,0}, aB1 = {0,0,0,0};
        #pragma unroll
        for (int cc = 0; cc < 2; ++cc) {
            FU ah, al;
            int aoff = m*32 + ((((unsigned)((4*cc + g4) ^ m)) & 7) << 2);
            ah.uv = *(const u32x4*)(YPw + aoff);
            al.uv = *(const u32x4*)(YPw + 512 + aoff);
            aA0 = MFMA16(ah.v, w1h[0][cc].v, aA0);
            aB0 = MFMA16(ah.v, w1l[0][cc].v, aB0);
            aA0 = MFMA16(al.v, w1h[0][cc].v, aA0);
            aA1 = MFMA16(ah.v, w1h[1][cc].v, aA1);
            aB1 = MFMA16(ah.v, w1l[1][cc].v, aB1);
            aA1 = MFMA16(al.v, w1h[1][cc].v, aA1);
        }
        // epilogue: +ie +t +bias, tanh, split, publish T planes
        #pragma unroll
        for (int r = 0; r < 4; ++r) {
            float er = __shfl(eAll, 4*g4 + r);
            const int row = 4*g4 + r;
            #pragma unroll
            for (int u = 0; u < 2; ++u) {
                float val = u ? (aA1[r] + aB1[r]) : (aA0[r] + aB0[r]);
                val = fmaf(w64c[u], er, val);
                val = fmaf(w65c[u], ts, val);
                val += b1c[u];
                float th = tanh_fast(val);
                ushort hs, ls; split2(th, hs, ls);
                unsigned hp = hs, lp = ls;
                unsigned hq = __shfl_xor(hp, 1), lq = __shfl_xor(lp, 1);
                if ((m & 1) == 0) {
                    int wgrp = 4*w + 2*u + (m >> 3);
                    int woff = row*128 + ((((unsigned)wgrp & 24) | (((unsigned)(wgrp ^ row)) & 7)) << 2)
                             + ((m >> 1) & 3);
                    TPw[woff]        = hp | (hq << 16);
                    TPw[2048 + woff] = lp | (lq << 16);
                }
            }
        }
        __syncthreads();   // B1: T planes ready

        // GEMM2 partial (K-half kh): A from T planes, B from registers
        f32x4 pA = {0,0,0,0}, pB = {0,0,0,0};
        #pragma unroll
        for (int cc = 0; cc < 4; ++cc) {
            FU ah, al;
            int G = 16*kh + 4*cc + g4;
            int aoff = m*128 + ((((unsigned)G & 24) | (((unsigned)(G ^ m)) & 7)) << 2);
            ah.uv = *(const u32x4*)(TPw + aoff);
            al.uv = *(const u32x4*)(TPw + 2048 + aoff);
            pA = MFMA16(ah.v, w2h[cc].v, pA);
            pB = MFMA16(ah.v, w2l[cc].v, pB);
            pA = MFMA16(al.v, w2h[cc].v, pA);
        }
        f32x4 pr = pA + pB;
        *(f32x4*)(PRT + w*320 + m*20 + 4*g4) = pr;
        __syncthreads();   // B2: partials ready

        const float* pb = PRT + m*20 + 4*g4;
        f32x4 q0 = *(const f32x4*)(pb + nt*320);
        f32x4 q1 = *(const f32x4*)(pb + (nt+4)*320);
        f32x4 qq = q0 + q1;
        dd[0] = qq[0] + b2c; dd[1] = qq[1] + b2c;
        dd[2] = qq[2] + b2c; dd[3] = qq[3] + b2c;
    };

    // ---- decode one (cc,el) row from committed Yf, LDS weights, reg-broadcast y ----
    auto decode_row = [&](int row, int tix) {
        const int cc = row % 3, el = row / 3;
        const int b  = blockIdx.x*4 + el;
        float dyv = Yf[row*65 + ln];
        float acc = DB1[cc*HD + ln];
        #pragma unroll 8
        for (int h = 0; h < 64; ++h)
            acc = fmaf(rdlane(dyv, h), DW1[(cc*HD + h)*HD + ln], acc);
        float hid = fmaxf(acc, 0.f);
        #pragma unroll
        for (int v = 0; v < NV; ++v) {
            float pv = wsum64(hid * DW2[(cc*HD + ln)*NV + v]);
            if (ln == 0)
                out[(((size_t)cc*BTOT + b)*TPTS + tix)*NV + v] = pv + DB2[cc*NV + v];
        }
    };
    auto decode = [&](int tix) {
        decode_row(w, tix);                 // rows 0-7
        if (w < 4) decode_row(w + 8, tix);  // rows 8-11
    };

    // ---- RK4 over 95 intervals ----
    decode(0);
    f32x4 dd;
    #pragma unroll 1
    for (int s = 0; s < TPTS - 1; ++s) {
        const float ta = tps[s], tb = tps[s + 1];
        const float dt = tb - ta, hdt = 0.5f * dt;

        evalf(ta, dd);
        ks = dd; publish(yb + hdt*dd, false);
        __syncthreads();   // B3: Y planes / PS ready

        evalf(ta + hdt, dd);
        ks += 2.f*dd; publish(yb + hdt*dd, false);
        __syncthreads();

        evalf(ta + hdt, dd);
        ks += 2.f*dd; publish(yb + dt*dd, false);
        __syncthreads();

        evalf(tb, dd);
        ks += dd; yb = yb + (dt*(1.f/6.f))*ks; publish(yb, true);
        __syncthreads();

        decode(s + 1);
    }
}

extern "C" void kernel_launch(void* const* d_in, const int* in_sizes, int n_in,
                              void* d_out, int out_size, void* d_ws, size_t ws_size,
                              hipStream_t stream) {
    const float* x     = (const float*)d_in[0];
    const float* iw1   = (const float*)d_in[1];
    const float* ib1   = (const float*)d_in[2];
    const float* iw2   = (const float*)d_in[3];
    const float* ib2   = (const float*)d_in[4];
    const float* ow1   = (const float*)d_in[5];
    const float* ob1   = (const float*)d_in[6];
    const float* ow2   = (const float*)d_in[7];
    const float* ob2   = (const float*)d_in[8];
    const float* inter = (const float*)d_in[9];
    const float* cons  = (const float*)d_in[10];
    const float* dw1   = (const float*)d_in[11];
    const float* db1   = (const float*)d_in[12];
    const float* dw2   = (const float*)d_in[13];
    const float* db2   = (const float*)d_in[14];
    const float* tpts  = (const float*)d_in[15];
    float* out = (float*)d_out;

    // dynamic LDS > 64 KB (host-side, graph-capture safe)
    (void)hipFuncSetAttribute((const void*)node_mfma13,
                              hipFuncAttributeMaxDynamicSharedMemorySize,
                              SMEM_BYTES);

    node_mfma13<<<BTOT / 4, 512, SMEM_BYTES, stream>>>(
        x, iw1, ib1, iw2, ib2, ow1, ob1, ow2, ob2,
        inter, cons, dw1, db1, dw2, db2, tpts, out);
}